// Round 10
// baseline (305.899 us; speedup 1.0000x reference)
//
#include <hip/hip_runtime.h>

#define TT 256
#define BB 512
#define DD 128
#define HH 50
#define KK 5
#define AA 4
#define NROW 131072      // T*B rows
#define GST 56           // g row stride (pass bases 0 and 28, 16B aligned)

#define R25(X) X(0) X(1) X(2) X(3) X(4) X(5) X(6) X(7) X(8) X(9) \
  X(10) X(11) X(12) X(13) X(14) X(15) X(16) X(17) X(18) X(19) \
  X(20) X(21) X(22) X(23) X(24)

typedef _Float16 half4 __attribute__((ext_vector_type(4)));
typedef float f32x4 __attribute__((ext_vector_type(4)));

// ---------------- K0: weight prep ----------------
__global__ void k0_prep(const float* __restrict__ W_in,
                        const float* __restrict__ W_ctx,
                        const float* __restrict__ W_key,
                        const float* __restrict__ W_q,
                        const float* __restrict__ b_key,
                        const float* __restrict__ b_q,
                        float* __restrict__ WT, float* __restrict__ WHT,
                        float* __restrict__ WK2T, float* __restrict__ bias2) {
  int i = blockIdx.x * 256 + threadIdx.x;
  if (i < DD * 52) {
    int j = i / 52, h = i % 52;
    WT[i] = (h < HH) ? W_in[h * DD + j] : 0.f;
  }
  if (i < HH * 52) {
    int j = i / 52, h = i % 52;
    WHT[i] = (h < HH) ? W_ctx[h * (2 * HH) + HH + j] : 0.f;
  }
  if (i < HH * 64) {
    int j = i >> 6, l = i & 63;
    float v = 0.f;
    if (l < HH) v = W_ctx[l * (2 * HH) + j];
    else if (l < HH + KK) v = W_key[(l - HH) * HH + j];
    else if (l < HH + 2 * KK) v = W_q[(l - HH - KK) * HH + j];
    WK2T[i] = v;
  }
  if (i < 64) {
    float bv = 0.f;
    if (i >= HH && i < HH + KK) bv = b_key[i - HH];
    else if (i >= HH + KK && i < HH + 2 * KK) bv = b_q[i - HH - KK];
    bias2[i] = bv;
  }
}

// ---------------- K1a: h = relu(x@W_in^T + b_in), 2 passes x 25 accums ----
// Writes h TRANSPOSED: hT[h][row] -> 25 fully-coalesced stores per pass.
__global__ __launch_bounds__(256) void k1a(const float* __restrict__ x,
                                           const float* __restrict__ WT,
                                           const float* __restrict__ b_in,
                                           float* __restrict__ hT) {
  __shared__ float xs[256 * 17];
  const int tid = threadIdx.x;
  const int row = blockIdx.x * 256 + tid;
  const float* __restrict__ xblk = x + (size_t)blockIdx.x * 256 * DD;

#pragma unroll 1
  for (int hp = 0; hp < 2; ++hp) {
    const int hb = hp * 25;
#define DECLA(i) float a##i = b_in[hb + i];
    R25(DECLA)

#pragma unroll 1
    for (int jb = 0; jb < 8; ++jb) {
      __syncthreads();
#pragma unroll
      for (int u = 0; u < 4; ++u) {
        const int f = tid + u * 256;
        const int r = f >> 2, c4 = f & 3;
        const float4 v = *reinterpret_cast<const float4*>(
            xblk + (size_t)r * DD + jb * 16 + c4 * 4);
        float* d = &xs[r * 17 + c4 * 4];
        d[0] = v.x; d[1] = v.y; d[2] = v.z; d[3] = v.w;
      }
      __syncthreads();
      const float* __restrict__ xrow = &xs[tid * 17];
#pragma unroll
      for (int cc = 0; cc < 16; cc += 4) {
        const int j = jb * 16 + cc;
        const float xv0 = xrow[cc + 0];
        const float xv1 = xrow[cc + 1];
        const float xv2 = xrow[cc + 2];
        const float xv3 = xrow[cc + 3];
        const float* __restrict__ w0 = WT + (j + 0) * 52 + hb;
        const float* __restrict__ w1 = WT + (j + 1) * 52 + hb;
        const float* __restrict__ w2 = WT + (j + 2) * 52 + hb;
        const float* __restrict__ w3 = WT + (j + 3) * 52 + hb;
#define FMA25(i)                  \
  a##i = fmaf(xv0, w0[i], a##i);  \
  a##i = fmaf(xv1, w1[i], a##i);  \
  a##i = fmaf(xv2, w2[i], a##i);  \
  a##i = fmaf(xv3, w3[i], a##i);
        R25(FMA25)
      }
    }

#define STA(i) hT[(size_t)(hb + i) * NROW + row] = fmaxf(a##i, 0.f);
    R25(STA)
  }
}

// ---------------- K1b: g = h @ Wh^T + b_ctx, 2 passes x 25 accums ----------
// h read coalesced from hT[h][row]; g written stride-56 (bases 0/28).
__global__ __launch_bounds__(256) void k1b(const float* __restrict__ hT,
                                           const float* __restrict__ WHT,
                                           const float* __restrict__ b_ctx,
                                           float* __restrict__ g) {
  const int row = blockIdx.x * 256 + threadIdx.x;

#pragma unroll 1
  for (int gp = 0; gp < 2; ++gp) {
    const int gb = gp * 25;
#define DECLG(i) float a##i = b_ctx[gb + i];
    R25(DECLG)

#pragma unroll 5
    for (int s = 0; s < HH; ++s) {
      const float hv = hT[(size_t)s * NROW + row];
      const float* __restrict__ wh = WHT + s * 52 + gb;
#define GFMA(i) a##i = fmaf(hv, wh[i], a##i);
      R25(GFMA)
    }

    float* __restrict__ gr = g + (size_t)row * GST + gp * 28;
    *reinterpret_cast<float4*>(gr + 0) = make_float4(a0, a1, a2, a3);
    *reinterpret_cast<float4*>(gr + 4) = make_float4(a4, a5, a6, a7);
    *reinterpret_cast<float4*>(gr + 8) = make_float4(a8, a9, a10, a11);
    *reinterpret_cast<float4*>(gr + 12) = make_float4(a12, a13, a14, a15);
    *reinterpret_cast<float4*>(gr + 16) = make_float4(a16, a17, a18, a19);
    *reinterpret_cast<float4*>(gr + 20) = make_float4(a20, a21, a22, a23);
    gr[24] = a24;
  }
}

// ---------------- K2: per-batch recurrence (512 blocks x 1 wave) -----------
// Weights in LDS (WL[lane][52], 16B-aligned rows); per-iter ds_read_b128
// kept in-loop via asm-laundered offset (low VGPR demand, allocator-proof).
// c broadcast via wave-uniform float4 LDS reads. lanes 0-49: c; 50-54: key;
// 55-59: q.
__global__ __launch_bounds__(64) void k2_rec(
    const float* __restrict__ g, const float* __restrict__ WK2T,
    const float* __restrict__ bias2, const float* __restrict__ first_context,
    float* __restrict__ ctxg, float* __restrict__ keyg,
    float* __restrict__ qg) {
  __shared__ __align__(16) float WL[64 * 52];
  __shared__ __align__(16) float c_lds[64];
  const int b = blockIdx.x;
  const int lane = threadIdx.x;

  // stage weights: WL[l][j] = WK2T[j*64 + l]; pad j=50,51 with 0
#pragma unroll 1
  for (int j = 0; j < HH; ++j) WL[lane * 52 + j] = WK2T[j * 64 + lane];
  WL[lane * 52 + 50] = 0.f;
  WL[lane * 52 + 51] = 0.f;
  const float bias = bias2[lane];

  const float c0v = (lane < HH) ? first_context[lane] : 0.f;
  c_lds[lane] = (lane < HH) ? c0v : 0.f;  // [50..63] stay 0 forever
  if (lane < HH) ctxg[((size_t)b * 257 + 0) * HH + lane] = c0v;

  const int gslot = lane + (lane >= 25 ? 3 : 0);  // k1b's stride-56 layout
  float gvA = (lane < HH) ? g[((size_t)(0 * BB + b)) * GST + gslot] : 0.f;
  float gvB = (lane < HH) ? g[((size_t)(1 * BB + b)) * GST + gslot] : 0.f;
  float gvC = (lane < HH) ? g[((size_t)(2 * BB + b)) * GST + gslot] : 0.f;

  const int wboff = lane * (52 * 4);

#define KQ(J)                                                            \
  {                                                                      \
    const float4 wq = *reinterpret_cast<const float4*>(wl + (J));        \
    const float4 cq = *reinterpret_cast<const float4*>(&c_lds[J]);       \
    acc0 = fmaf(wq.x, cq.x, acc0);                                       \
    acc1 = fmaf(wq.y, cq.y, acc1);                                       \
    acc2 = fmaf(wq.z, cq.z, acc2);                                       \
    acc3 = fmaf(wq.w, cq.w, acc3);                                       \
  }
#define DOT50LDS                                                         \
  int wb = wboff;                                                        \
  asm volatile("" : "+v"(wb));                                           \
  const float* wl =                                                      \
      reinterpret_cast<const float*>(reinterpret_cast<const char*>(WL) + wb); \
  float acc0 = 0.f, acc1 = 0.f, acc2 = 0.f, acc3 = 0.f;                  \
  KQ(0) KQ(4) KQ(8) KQ(12) KQ(16) KQ(20) KQ(24) KQ(28) KQ(32) KQ(36)    \
  KQ(40) KQ(44) KQ(48)                                                   \
  const float acc = (acc0 + acc1) + (acc2 + acc3);

#pragma unroll 1
  for (int t = 0; t < TT; ++t) {
    float gvn = 0.f;
    if (lane < HH && (t + 3) < TT)
      gvn = g[((size_t)((t + 3) * BB + b)) * GST + gslot];

    DOT50LDS

    if (lane >= HH && lane < HH + KK)
      keyg[((size_t)b * KK + (lane - HH)) * 257 + t] = acc + bias;
    if (lane >= HH + KK && lane < HH + 2 * KK && t >= 1)
      qg[((size_t)b * KK + (lane - HH - KK)) * 256 + (t - 1)] = acc + bias;

    const float cn = fmaxf(acc + gvA, 0.f);
    gvA = gvB;
    gvB = gvC;
    gvC = gvn;
    if (lane < HH) {
      ctxg[((size_t)b * 257 + (t + 1)) * HH + lane] = cn;
      c_lds[lane] = cn;  // in-wave DS ordering: visible next iter
    }
  }

  {  // tail t = TT: key[TT] and q[TT-1]
    DOT50LDS
    if (lane >= HH && lane < HH + KK)
      keyg[((size_t)b * KK + (lane - HH)) * 257 + TT] = acc + bias;
    if (lane >= HH + KK && lane < HH + 2 * KK)
      qg[((size_t)b * KK + (lane - HH - KK)) * 256 + (TT - 1)] = acc + bias;
  }
}

// ---------------- K3: MFMA flash attention, LDS-staged (unchanged R9) -----
__global__ __launch_bounds__(256, 4) void k3_attn(
    const float* __restrict__ ctxg, const float* __restrict__ keyg,
    const float* __restrict__ qg, const float* __restrict__ W_act,
    const float* __restrict__ b_act, float* __restrict__ out) {
  __shared__ __align__(16) float ct[64 * 66];   // [s_local][h]
  __shared__ __align__(16) float k_l[8 * 68];   // [k][s_local], rows 5-7 = 0
  __shared__ __align__(16) float o_l[64 * 66];  // [t_local][h]
  __shared__ float su_l[64];

  const int tid = threadIdx.x;
  const int bid = blockIdx.x;
  const int chunk = 3 - (bid >> 9);  // heavy-first
  const int b = bid & 511;
  const int tbase = chunk * 64;
  const int nst = min(tbase + 66, 257);
  const int ntiles = (nst + 63) >> 6;
  const int wave = tid >> 6;
  const int lane = tid & 63;
  const int lrow = lane & 15;
  const int lgrp = lane >> 4;
  const int tw = tbase + wave * 16;

  if (tid < 3 * 68) k_l[5 * 68 + tid] = 0.f;

  half4 qf;
#pragma unroll
  for (int i = 0; i < 4; ++i) {
    const int k = 4 * lgrp + i;
    qf[i] = (_Float16)((k < KK) ? qg[((size_t)b * KK + k) * 256 + tw + lrow]
                                : 0.f);
  }

  const f32x4 zf = {0.f, 0.f, 0.f, 0.f};
  f32x4 acc0 = zf, acc1 = zf, acc2 = zf, acc3 = zf;
  float su = 0.f;

#pragma unroll 1
  for (int tile = 0; tile < ntiles; ++tile) {
    __syncthreads();
    {
      const int r = tid >> 2;
      const int c0 = (tid & 3) * 16;
      const int srow = tile * 64 + r;
      const float* src = ctxg + ((size_t)b * 257 + srow) * HH;
      const bool sv = (srow < nst);
#pragma unroll
      for (int u = 0; u < 8; ++u) {
        const int c = c0 + u * 2;
        float2 v = make_float2(0.f, 0.f);
        if (sv && c < HH) v = *reinterpret_cast<const float2*>(src + c);
        *reinterpret_cast<float2*>(&ct[r * 66 + c]) = v;
      }
    }
    {
      for (int i = tid; i < KK * 64; i += 256) {
        const int k = i >> 6, sl = i & 63;
        const int s = tile * 64 + sl;
        k_l[k * 68 + sl] =
            (s <= TT) ? keyg[((size_t)b * KK + k) * 257 + s] : 0.f;
      }
    }
    __syncthreads();

    if (tile * 64 <= tw + 16) {
#pragma unroll 1
      for (int su16 = 0; su16 < 4; ++su16) {
        const int sb = tile * 64 + su16 * 16;
        if (sb > tw + 16) break;

        half4 kf;
#pragma unroll
        for (int i = 0; i < 4; ++i)
          kf[i] = (_Float16)k_l[(4 * lgrp + i) * 68 + su16 * 16 + lrow];

        const f32x4 sc =
            __builtin_amdgcn_mfma_f32_16x16x16f16(kf, qf, zf, 0, 0, 0);

        half4 pa;
#pragma unroll
        for (int r = 0; r < 4; ++r) {
          const int s = sb + 4 * lgrp + r;
          const float p = (s <= tw + lrow + 1) ? __expf(sc[r]) : 0.f;
          su += p;
          pa[r] = (_Float16)p;
        }

        const int vbase = su16 * 16 + 4 * lgrp;
#define PVHT(HT, ACC)                                                     \
  {                                                                       \
    half4 vf;                                                             \
    vf[0] = (_Float16)ct[(vbase + 0) * 66 + lrow + 16 * HT];              \
    vf[1] = (_Float16)ct[(vbase + 1) * 66 + lrow + 16 * HT];              \
    vf[2] = (_Float16)ct[(vbase + 2) * 66 + lrow + 16 * HT];              \
    vf[3] = (_Float16)ct[(vbase + 3) * 66 + lrow + 16 * HT];              \
    ACC = __builtin_amdgcn_mfma_f32_16x16x16f16(pa, vf, ACC, 0, 0, 0);    \
  }
        PVHT(0, acc0) PVHT(1, acc1) PVHT(2, acc2) PVHT(3, acc3)
      }
    }
  }

  su += __shfl_xor(su, 16, 64);
  su += __shfl_xor(su, 32, 64);
  if (lane < 16) su_l[wave * 16 + lane] = su;

#pragma unroll
  for (int r = 0; r < 4; ++r) {
    const int trow = wave * 16 + 4 * lgrp + r;
    o_l[trow * 66 + lrow + 0] = acc0[r];
    o_l[trow * 66 + lrow + 16] = acc1[r];
    o_l[trow * 66 + lrow + 32] = acc2[r];
    o_l[trow * 66 + lrow + 48] = acc3[r];
  }
  __syncthreads();

  {
    const int tl = tid >> 2;
    const int a = tid & 3;
    const float inv = 1.f / su_l[tl];
    const float* orow = &o_l[tl * 66];
    const float* wrow = W_act + a * HH;
    float s0 = 0.f, s1 = 0.f;
#pragma unroll
    for (int h = 0; h < HH; h += 2) {
      s0 = fmaf(orow[h], wrow[h], s0);
      s1 = fmaf(orow[h + 1], wrow[h + 1], s1);
    }
    out[((size_t)(tbase + tl) * BB + b) * AA + a] =
        fmaf(s0 + s1, inv, b_act[a]);
  }
}

extern "C" void kernel_launch(void* const* d_in, const int* in_sizes, int n_in,
                              void* d_out, int out_size, void* d_ws,
                              size_t ws_size, hipStream_t stream) {
  const float* x = (const float*)d_in[0];
  const float* W_in = (const float*)d_in[1];
  const float* b_in = (const float*)d_in[2];
  const float* W_ctx = (const float*)d_in[3];
  const float* b_ctx = (const float*)d_in[4];
  const float* W_key = (const float*)d_in[5];
  const float* b_key = (const float*)d_in[6];
  const float* W_q = (const float*)d_in[7];
  const float* b_q = (const float*)d_in[8];
  const float* fc = (const float*)d_in[9];
  const float* W_act = (const float*)d_in[10];
  const float* b_act = (const float*)d_in[11];
  float* out = (float*)d_out;
  float* ws = (float*)d_ws;

  float* WT = ws;                                  // 128*52
  float* WHT = ws + 8192;                          // 50*52
  float* WK2T = ws + 12288;                        // 50*64
  float* bias2 = ws + 15616;                       // 64
  float* g = ws + 16384;                           // 131072*56
  float* hbufT = g + (size_t)NROW * GST;           // region 512*257*50 floats
  float* ctxg = hbufT;                             // alias: hbufT dead after k1b
  float* keyg = hbufT + (size_t)BB * 257 * HH;     // 512*5*257
  float* qg = keyg + (size_t)BB * KK * 257;        // 512*5*256
  // total ~61.0 MB

  hipLaunchKernelGGL(k0_prep, dim3(26), dim3(256), 0, stream, W_in, W_ctx,
                     W_key, W_q, b_key, b_q, WT, WHT, WK2T, bias2);
  hipLaunchKernelGGL(k1a, dim3(512), dim3(256), 0, stream, x, WT, b_in, hbufT);
  hipLaunchKernelGGL(k1b, dim3(512), dim3(256), 0, stream, hbufT, WHT, b_ctx,
                     g);
  hipLaunchKernelGGL(k2_rec, dim3(512), dim3(64), 0, stream, g, WK2T, bias2,
                     fc, ctxg, keyg, qg);
  hipLaunchKernelGGL(k3_attn, dim3(2048), dim3(256), 0, stream, ctxg, keyg, qg,
                     W_act, b_act, out);
}

// Round 11
// 255.336 us; speedup vs baseline: 1.1980x; 1.1980x over previous
//
#include <hip/hip_runtime.h>

#define TT 256
#define BB 512
#define DD 128
#define HH 50
#define KK 5
#define AA 4
#define NROW 131072      // T*B rows
#define GST 56           // g row stride (pass bases 0 and 28, 16B aligned)

#define R25(X) X(0) X(1) X(2) X(3) X(4) X(5) X(6) X(7) X(8) X(9) \
  X(10) X(11) X(12) X(13) X(14) X(15) X(16) X(17) X(18) X(19) \
  X(20) X(21) X(22) X(23) X(24)

typedef _Float16 half4 __attribute__((ext_vector_type(4)));
typedef float f32x4 __attribute__((ext_vector_type(4)));

// ---------------- K0: weight prep ----------------
__global__ void k0_prep(const float* __restrict__ W_in,
                        const float* __restrict__ W_ctx,
                        const float* __restrict__ W_key,
                        const float* __restrict__ W_q,
                        const float* __restrict__ b_key,
                        const float* __restrict__ b_q,
                        float* __restrict__ WT, float* __restrict__ WHT,
                        float* __restrict__ WK2T, float* __restrict__ bias2) {
  int i = blockIdx.x * 256 + threadIdx.x;
  if (i < DD * 52) {
    int j = i / 52, h = i % 52;
    WT[i] = (h < HH) ? W_in[h * DD + j] : 0.f;
  }
  if (i < HH * 52) {
    int j = i / 52, h = i % 52;
    WHT[i] = (h < HH) ? W_ctx[h * (2 * HH) + HH + j] : 0.f;
  }
  if (i < HH * 64) {
    int j = i >> 6, l = i & 63;
    float v = 0.f;
    if (l < HH) v = W_ctx[l * (2 * HH) + j];
    else if (l < HH + KK) v = W_key[(l - HH) * HH + j];
    else if (l < HH + 2 * KK) v = W_q[(l - HH - KK) * HH + j];
    WK2T[i] = v;
  }
  if (i < 64) {
    float bv = 0.f;
    if (i >= HH && i < HH + KK) bv = b_key[i - HH];
    else if (i >= HH + KK && i < HH + 2 * KK) bv = b_q[i - HH - KK];
    bias2[i] = bv;
  }
}

// ---------------- K1a: h = relu(x@W_in^T + b_in), 2 passes x 25 accums ----
__global__ __launch_bounds__(256) void k1a(const float* __restrict__ x,
                                           const float* __restrict__ WT,
                                           const float* __restrict__ b_in,
                                           float* __restrict__ hT) {
  __shared__ float xs[256 * 17];
  const int tid = threadIdx.x;
  const int row = blockIdx.x * 256 + tid;
  const float* __restrict__ xblk = x + (size_t)blockIdx.x * 256 * DD;

#pragma unroll 1
  for (int hp = 0; hp < 2; ++hp) {
    const int hb = hp * 25;
#define DECLA(i) float a##i = b_in[hb + i];
    R25(DECLA)

#pragma unroll 1
    for (int jb = 0; jb < 8; ++jb) {
      __syncthreads();
#pragma unroll
      for (int u = 0; u < 4; ++u) {
        const int f = tid + u * 256;
        const int r = f >> 2, c4 = f & 3;
        const float4 v = *reinterpret_cast<const float4*>(
            xblk + (size_t)r * DD + jb * 16 + c4 * 4);
        float* d = &xs[r * 17 + c4 * 4];
        d[0] = v.x; d[1] = v.y; d[2] = v.z; d[3] = v.w;
      }
      __syncthreads();
      const float* __restrict__ xrow = &xs[tid * 17];
#pragma unroll
      for (int cc = 0; cc < 16; cc += 4) {
        const int j = jb * 16 + cc;
        const float xv0 = xrow[cc + 0];
        const float xv1 = xrow[cc + 1];
        const float xv2 = xrow[cc + 2];
        const float xv3 = xrow[cc + 3];
        const float* __restrict__ w0 = WT + (j + 0) * 52 + hb;
        const float* __restrict__ w1 = WT + (j + 1) * 52 + hb;
        const float* __restrict__ w2 = WT + (j + 2) * 52 + hb;
        const float* __restrict__ w3 = WT + (j + 3) * 52 + hb;
#define FMA25(i)                  \
  a##i = fmaf(xv0, w0[i], a##i);  \
  a##i = fmaf(xv1, w1[i], a##i);  \
  a##i = fmaf(xv2, w2[i], a##i);  \
  a##i = fmaf(xv3, w3[i], a##i);
        R25(FMA25)
      }
    }

#define STA(i) hT[(size_t)(hb + i) * NROW + row] = fmaxf(a##i, 0.f);
    R25(STA)
  }
}

// ---------------- K1b: g = h @ Wh^T + b_ctx, 2 passes x 25 accums ----------
// h read coalesced from hT[h][row]; g written TRANSPOSED per chain:
// g[(b*TT + t)*GST + slot]  (row = t*BB + b  ->  b = row&511, t = row>>9).
__global__ __launch_bounds__(256) void k1b(const float* __restrict__ hT,
                                           const float* __restrict__ WHT,
                                           const float* __restrict__ b_ctx,
                                           float* __restrict__ g) {
  const int row = blockIdx.x * 256 + threadIdx.x;
  const int b = row & (BB - 1);
  const int t = row >> 9;

#pragma unroll 1
  for (int gp = 0; gp < 2; ++gp) {
    const int gb = gp * 25;
#define DECLG(i) float a##i = b_ctx[gb + i];
    R25(DECLG)

#pragma unroll 5
    for (int s = 0; s < HH; ++s) {
      const float hv = hT[(size_t)s * NROW + row];
      const float* __restrict__ wh = WHT + s * 52 + gb;
#define GFMA(i) a##i = fmaf(hv, wh[i], a##i);
      R25(GFMA)
    }

    float* __restrict__ gr = g + ((size_t)b * TT + t) * GST + gp * 28;
    *reinterpret_cast<float4*>(gr + 0) = make_float4(a0, a1, a2, a3);
    *reinterpret_cast<float4*>(gr + 4) = make_float4(a4, a5, a6, a7);
    *reinterpret_cast<float4*>(gr + 8) = make_float4(a8, a9, a10, a11);
    *reinterpret_cast<float4*>(gr + 12) = make_float4(a12, a13, a14, a15);
    *reinterpret_cast<float4*>(gr + 16) = make_float4(a16, a17, a18, a19);
    *reinterpret_cast<float4*>(gr + 20) = make_float4(a20, a21, a22, a23);
    gr[24] = a24;
  }
}

// ---------------- K2: per-batch recurrence (512 blocks x 1 wave) -----------
// 4-body manual unroll with NAMED prefetch regs gq0..gq3: each body consumes
// gqR then reloads it UNCONDITIONALLY (min-clamped index, no select) -> the
// load defines the register directly and its s_waitcnt lands 4 bodies
// (~1400cy) later, covering HBM latency. g is per-chain contiguous now.
// Weights in LDS (WL[lane][52]); c broadcast via wave-uniform float4 reads.
// lanes 0-49: c; 50-54: key; 55-59: q.
__global__ __launch_bounds__(64) void k2_rec(
    const float* __restrict__ g, const float* __restrict__ WK2T,
    const float* __restrict__ bias2, const float* __restrict__ first_context,
    float* __restrict__ ctxg, float* __restrict__ keyg,
    float* __restrict__ qg) {
  __shared__ __align__(16) float WL[64 * 52];
  __shared__ __align__(16) float c_lds[64];
  const int b = blockIdx.x;
  const int lane = threadIdx.x;

#pragma unroll 4
  for (int j = 0; j < HH; ++j) WL[lane * 52 + j] = WK2T[j * 64 + lane];
  WL[lane * 52 + 50] = 0.f;
  WL[lane * 52 + 51] = 0.f;
  const float bias = bias2[lane];

  const float c0v = (lane < HH) ? first_context[lane] : 0.f;
  c_lds[lane] = (lane < HH) ? c0v : 0.f;  // [50..63] stay 0 forever
  if (lane < HH) ctxg[((size_t)b * 257 + 0) * HH + lane] = c0v;

  const int gslot = lane + (lane >= 25 ? 3 : 0);  // k1b's stride-56 layout
  const float* __restrict__ gbp = g + (size_t)b * TT * GST + gslot;
  // unconditional preloads (lanes >= 50 read junk in-bounds; never consumed)
  float gq0 = gbp[0 * GST];
  float gq1 = gbp[1 * GST];
  float gq2 = gbp[2 * GST];
  float gq3 = gbp[3 * GST];

  const int wboff = lane * (52 * 4);

#define KQ(J)                                                            \
  {                                                                      \
    const float4 wq = *reinterpret_cast<const float4*>(wl + (J));        \
    const float4 cq = *reinterpret_cast<const float4*>(&c_lds[J]);       \
    acc0 = fmaf(wq.x, cq.x, acc0);                                       \
    acc1 = fmaf(wq.y, cq.y, acc1);                                       \
    acc2 = fmaf(wq.z, cq.z, acc2);                                       \
    acc3 = fmaf(wq.w, cq.w, acc3);                                       \
  }
#define DOT50LDS                                                         \
  int wb = wboff;                                                        \
  asm volatile("" : "+v"(wb));                                           \
  const float* wl =                                                      \
      reinterpret_cast<const float*>(reinterpret_cast<const char*>(WL) + wb); \
  float acc0 = 0.f, acc1 = 0.f, acc2 = 0.f, acc3 = 0.f;                  \
  KQ(0) KQ(4) KQ(8) KQ(12) KQ(16) KQ(20) KQ(24) KQ(28) KQ(32) KQ(36)    \
  KQ(40) KQ(44) KQ(48)                                                   \
  const float acc = (acc0 + acc1) + (acc2 + acc3);

#define BODY(RR, GQ)                                                     \
  {                                                                      \
    const int t = tg4 + RR;                                              \
    DOT50LDS                                                             \
    if (lane >= HH && lane < HH + KK)                                    \
      keyg[((size_t)b * KK + (lane - HH)) * 257 + t] = acc + bias;       \
    if (lane >= HH + KK && lane < HH + 2 * KK && t >= 1)                 \
      qg[((size_t)b * KK + (lane - HH - KK)) * 256 + (t - 1)] =          \
          acc + bias;                                                    \
    const float cn = fmaxf(acc + GQ, 0.f);                               \
    GQ = gbp[(size_t)min(t + 4, TT - 1) * GST]; /* uncond, direct def */ \
    if (lane < HH) {                                                     \
      ctxg[((size_t)b * 257 + (t + 1)) * HH + lane] = cn;                \
      c_lds[lane] = cn;  /* in-wave DS order: visible next body */       \
    }                                                                    \
  }

#pragma unroll 1
  for (int tg4 = 0; tg4 < TT; tg4 += 4) {
    BODY(0, gq0) BODY(1, gq1) BODY(2, gq2) BODY(3, gq3)
  }

  {  // tail t = TT: key[TT] of c_TT, and q[TT-1]
    DOT50LDS
    if (lane >= HH && lane < HH + KK)
      keyg[((size_t)b * KK + (lane - HH)) * 257 + TT] = acc + bias;
    if (lane >= HH + KK && lane < HH + 2 * KK)
      qg[((size_t)b * KK + (lane - HH - KK)) * 256 + (TT - 1)] = acc + bias;
  }
}

// ---------------- K3: MFMA flash attention, LDS-staged (unchanged) --------
__global__ __launch_bounds__(256, 4) void k3_attn(
    const float* __restrict__ ctxg, const float* __restrict__ keyg,
    const float* __restrict__ qg, const float* __restrict__ W_act,
    const float* __restrict__ b_act, float* __restrict__ out) {
  __shared__ __align__(16) float ct[64 * 66];   // [s_local][h]
  __shared__ __align__(16) float k_l[8 * 68];   // [k][s_local], rows 5-7 = 0
  __shared__ __align__(16) float o_l[64 * 66];  // [t_local][h]
  __shared__ float su_l[64];

  const int tid = threadIdx.x;
  const int bid = blockIdx.x;
  const int chunk = 3 - (bid >> 9);  // heavy-first
  const int b = bid & 511;
  const int tbase = chunk * 64;
  const int nst = min(tbase + 66, 257);
  const int ntiles = (nst + 63) >> 6;
  const int wave = tid >> 6;
  const int lane = tid & 63;
  const int lrow = lane & 15;
  const int lgrp = lane >> 4;
  const int tw = tbase + wave * 16;

  if (tid < 3 * 68) k_l[5 * 68 + tid] = 0.f;

  half4 qf;
#pragma unroll
  for (int i = 0; i < 4; ++i) {
    const int k = 4 * lgrp + i;
    qf[i] = (_Float16)((k < KK) ? qg[((size_t)b * KK + k) * 256 + tw + lrow]
                                : 0.f);
  }

  const f32x4 zf = {0.f, 0.f, 0.f, 0.f};
  f32x4 acc0 = zf, acc1 = zf, acc2 = zf, acc3 = zf;
  float su = 0.f;

#pragma unroll 1
  for (int tile = 0; tile < ntiles; ++tile) {
    __syncthreads();
    {
      const int r = tid >> 2;
      const int c0 = (tid & 3) * 16;
      const int srow = tile * 64 + r;
      const float* src = ctxg + ((size_t)b * 257 + srow) * HH;
      const bool sv = (srow < nst);
#pragma unroll
      for (int u = 0; u < 8; ++u) {
        const int c = c0 + u * 2;
        float2 v = make_float2(0.f, 0.f);
        if (sv && c < HH) v = *reinterpret_cast<const float2*>(src + c);
        *reinterpret_cast<float2*>(&ct[r * 66 + c]) = v;
      }
    }
    {
      for (int i = tid; i < KK * 64; i += 256) {
        const int k = i >> 6, sl = i & 63;
        const int s = tile * 64 + sl;
        k_l[k * 68 + sl] =
            (s <= TT) ? keyg[((size_t)b * KK + k) * 257 + s] : 0.f;
      }
    }
    __syncthreads();

    if (tile * 64 <= tw + 16) {
#pragma unroll 1
      for (int su16 = 0; su16 < 4; ++su16) {
        const int sb = tile * 64 + su16 * 16;
        if (sb > tw + 16) break;

        half4 kf;
#pragma unroll
        for (int i = 0; i < 4; ++i)
          kf[i] = (_Float16)k_l[(4 * lgrp + i) * 68 + su16 * 16 + lrow];

        const f32x4 sc =
            __builtin_amdgcn_mfma_f32_16x16x16f16(kf, qf, zf, 0, 0, 0);

        half4 pa;
#pragma unroll
        for (int r = 0; r < 4; ++r) {
          const int s = sb + 4 * lgrp + r;
          const float p = (s <= tw + lrow + 1) ? __expf(sc[r]) : 0.f;
          su += p;
          pa[r] = (_Float16)p;
        }

        const int vbase = su16 * 16 + 4 * lgrp;
#define PVHT(HT, ACC)                                                     \
  {                                                                       \
    half4 vf;                                                             \
    vf[0] = (_Float16)ct[(vbase + 0) * 66 + lrow + 16 * HT];              \
    vf[1] = (_Float16)ct[(vbase + 1) * 66 + lrow + 16 * HT];              \
    vf[2] = (_Float16)ct[(vbase + 2) * 66 + lrow + 16 * HT];              \
    vf[3] = (_Float16)ct[(vbase + 3) * 66 + lrow + 16 * HT];              \
    ACC = __builtin_amdgcn_mfma_f32_16x16x16f16(pa, vf, ACC, 0, 0, 0);    \
  }
        PVHT(0, acc0) PVHT(1, acc1) PVHT(2, acc2) PVHT(3, acc3)
      }
    }
  }

  su += __shfl_xor(su, 16, 64);
  su += __shfl_xor(su, 32, 64);
  if (lane < 16) su_l[wave * 16 + lane] = su;

#pragma unroll
  for (int r = 0; r < 4; ++r) {
    const int trow = wave * 16 + 4 * lgrp + r;
    o_l[trow * 66 + lrow + 0] = acc0[r];
    o_l[trow * 66 + lrow + 16] = acc1[r];
    o_l[trow * 66 + lrow + 32] = acc2[r];
    o_l[trow * 66 + lrow + 48] = acc3[r];
  }
  __syncthreads();

  {
    const int tl = tid >> 2;
    const int a = tid & 3;
    const float inv = 1.f / su_l[tl];
    const float* orow = &o_l[tl * 66];
    const float* wrow = W_act + a * HH;
    float s0 = 0.f, s1 = 0.f;
#pragma unroll
    for (int h = 0; h < HH; h += 2) {
      s0 = fmaf(orow[h], wrow[h], s0);
      s1 = fmaf(orow[h + 1], wrow[h + 1], s1);
    }
    out[((size_t)(tbase + tl) * BB + b) * AA + a] =
        fmaf(s0 + s1, inv, b_act[a]);
  }
}

extern "C" void kernel_launch(void* const* d_in, const int* in_sizes, int n_in,
                              void* d_out, int out_size, void* d_ws,
                              size_t ws_size, hipStream_t stream) {
  const float* x = (const float*)d_in[0];
  const float* W_in = (const float*)d_in[1];
  const float* b_in = (const float*)d_in[2];
  const float* W_ctx = (const float*)d_in[3];
  const float* b_ctx = (const float*)d_in[4];
  const float* W_key = (const float*)d_in[5];
  const float* b_key = (const float*)d_in[6];
  const float* W_q = (const float*)d_in[7];
  const float* b_q = (const float*)d_in[8];
  const float* fc = (const float*)d_in[9];
  const float* W_act = (const float*)d_in[10];
  const float* b_act = (const float*)d_in[11];
  float* out = (float*)d_out;
  float* ws = (float*)d_ws;

  float* WT = ws;                                  // 128*52
  float* WHT = ws + 8192;                          // 50*52
  float* WK2T = ws + 12288;                        // 50*64
  float* bias2 = ws + 15616;                       // 64
  float* g = ws + 16384;                           // 131072*56 (+64 pad)
  float* hbufT = g + (size_t)NROW * GST + 64;      // 50*131072
  float* ctxg = hbufT;                             // alias: dead after k1b
  float* keyg = hbufT + (size_t)BB * 257 * HH;     // 512*5*257
  float* qg = keyg + (size_t)BB * KK * 257;        // 512*5*256
  // total ~61 MB

  hipLaunchKernelGGL(k0_prep, dim3(26), dim3(256), 0, stream, W_in, W_ctx,
                     W_key, W_q, b_key, b_q, WT, WHT, WK2T, bias2);
  hipLaunchKernelGGL(k1a, dim3(512), dim3(256), 0, stream, x, WT, b_in, hbufT);
  hipLaunchKernelGGL(k1b, dim3(512), dim3(256), 0, stream, hbufT, WHT, b_ctx,
                     g);
  hipLaunchKernelGGL(k2_rec, dim3(512), dim3(64), 0, stream, g, WK2T, bias2,
                     fc, ctxg, keyg, qg);
  hipLaunchKernelGGL(k3_attn, dim3(2048), dim3(256), 0, stream, ctxg, keyg, qg,
                     W_act, b_act, out);
}

// Round 12
// 246.866 us; speedup vs baseline: 1.2391x; 1.0343x over previous
//
#include <hip/hip_runtime.h>

#define TT 256
#define BB 512
#define DD 128
#define HH 50
#define KK 5
#define AA 4
#define NROW 131072      // T*B rows
#define GST 56           // g row stride (pass bases 0 and 28, 16B aligned)

#define R25(X) X(0) X(1) X(2) X(3) X(4) X(5) X(6) X(7) X(8) X(9) \
  X(10) X(11) X(12) X(13) X(14) X(15) X(16) X(17) X(18) X(19) \
  X(20) X(21) X(22) X(23) X(24)
#define R50(X) X(0) X(1) X(2) X(3) X(4) X(5) X(6) X(7) X(8) X(9) \
  X(10) X(11) X(12) X(13) X(14) X(15) X(16) X(17) X(18) X(19) \
  X(20) X(21) X(22) X(23) X(24) X(25) X(26) X(27) X(28) X(29) \
  X(30) X(31) X(32) X(33) X(34) X(35) X(36) X(37) X(38) X(39) \
  X(40) X(41) X(42) X(43) X(44) X(45) X(46) X(47) X(48) X(49)

typedef _Float16 half4 __attribute__((ext_vector_type(4)));
typedef float f32x4 __attribute__((ext_vector_type(4)));

// ---------------- K0: weight prep ----------------
__global__ void k0_prep(const float* __restrict__ W_in,
                        const float* __restrict__ W_ctx,
                        const float* __restrict__ W_key,
                        const float* __restrict__ W_q,
                        const float* __restrict__ b_key,
                        const float* __restrict__ b_q,
                        float* __restrict__ WT, float* __restrict__ WHT,
                        float* __restrict__ WK2T, float* __restrict__ bias2) {
  int i = blockIdx.x * 256 + threadIdx.x;
  if (i < DD * 52) {
    int j = i / 52, h = i % 52;
    WT[i] = (h < HH) ? W_in[h * DD + j] : 0.f;
  }
  if (i < HH * 52) {
    int j = i / 52, h = i % 52;
    WHT[i] = (h < HH) ? W_ctx[h * (2 * HH) + HH + j] : 0.f;
  }
  if (i < HH * 64) {
    int j = i >> 6, l = i & 63;
    float v = 0.f;
    if (l < HH) v = W_ctx[l * (2 * HH) + j];
    else if (l < HH + KK) v = W_key[(l - HH) * HH + j];
    else if (l < HH + 2 * KK) v = W_q[(l - HH - KK) * HH + j];
    WK2T[i] = v;
  }
  if (i < 64) {
    float bv = 0.f;
    if (i >= HH && i < HH + KK) bv = b_key[i - HH];
    else if (i >= HH + KK && i < HH + 2 * KK) bv = b_q[i - HH - KK];
    bias2[i] = bv;
  }
}

// ---------------- K1a: h = relu(x@W_in^T + b_in), 2 passes x 25 accums ----
__global__ __launch_bounds__(256) void k1a(const float* __restrict__ x,
                                           const float* __restrict__ WT,
                                           const float* __restrict__ b_in,
                                           float* __restrict__ hT) {
  __shared__ float xs[256 * 17];
  const int tid = threadIdx.x;
  const int row = blockIdx.x * 256 + tid;
  const float* __restrict__ xblk = x + (size_t)blockIdx.x * 256 * DD;

#pragma unroll 1
  for (int hp = 0; hp < 2; ++hp) {
    const int hb = hp * 25;
#define DECLA(i) float a##i = b_in[hb + i];
    R25(DECLA)

#pragma unroll 1
    for (int jb = 0; jb < 8; ++jb) {
      __syncthreads();
#pragma unroll
      for (int u = 0; u < 4; ++u) {
        const int f = tid + u * 256;
        const int r = f >> 2, c4 = f & 3;
        const float4 v = *reinterpret_cast<const float4*>(
            xblk + (size_t)r * DD + jb * 16 + c4 * 4);
        float* d = &xs[r * 17 + c4 * 4];
        d[0] = v.x; d[1] = v.y; d[2] = v.z; d[3] = v.w;
      }
      __syncthreads();
      const float* __restrict__ xrow = &xs[tid * 17];
#pragma unroll
      for (int cc = 0; cc < 16; cc += 4) {
        const int j = jb * 16 + cc;
        const float xv0 = xrow[cc + 0];
        const float xv1 = xrow[cc + 1];
        const float xv2 = xrow[cc + 2];
        const float xv3 = xrow[cc + 3];
        const float* __restrict__ w0 = WT + (j + 0) * 52 + hb;
        const float* __restrict__ w1 = WT + (j + 1) * 52 + hb;
        const float* __restrict__ w2 = WT + (j + 2) * 52 + hb;
        const float* __restrict__ w3 = WT + (j + 3) * 52 + hb;
#define FMA25(i)                  \
  a##i = fmaf(xv0, w0[i], a##i);  \
  a##i = fmaf(xv1, w1[i], a##i);  \
  a##i = fmaf(xv2, w2[i], a##i);  \
  a##i = fmaf(xv3, w3[i], a##i);
        R25(FMA25)
      }
    }

#define STA(i) hT[(size_t)(hb + i) * NROW + row] = fmaxf(a##i, 0.f);
    R25(STA)
  }
}

// ---------------- K1b: g = h @ Wh^T + b_ctx, 2 passes x 25 accums ----------
__global__ __launch_bounds__(256) void k1b(const float* __restrict__ hT,
                                           const float* __restrict__ WHT,
                                           const float* __restrict__ b_ctx,
                                           float* __restrict__ g) {
  const int row = blockIdx.x * 256 + threadIdx.x;
  const int b = row & (BB - 1);
  const int t = row >> 9;

#pragma unroll 1
  for (int gp = 0; gp < 2; ++gp) {
    const int gb = gp * 25;
#define DECLG(i) float a##i = b_ctx[gb + i];
    R25(DECLG)

#pragma unroll 5
    for (int s = 0; s < HH; ++s) {
      const float hv = hT[(size_t)s * NROW + row];
      const float* __restrict__ wh = WHT + s * 52 + gb;
#define GFMA(i) a##i = fmaf(hv, wh[i], a##i);
      R25(GFMA)
    }

    float* __restrict__ gr = g + ((size_t)b * TT + t) * GST + gp * 28;
    *reinterpret_cast<float4*>(gr + 0) = make_float4(a0, a1, a2, a3);
    *reinterpret_cast<float4*>(gr + 4) = make_float4(a4, a5, a6, a7);
    *reinterpret_cast<float4*>(gr + 8) = make_float4(a8, a9, a10, a11);
    *reinterpret_cast<float4*>(gr + 12) = make_float4(a12, a13, a14, a15);
    *reinterpret_cast<float4*>(gr + 16) = make_float4(a16, a17, a18, a19);
    *reinterpret_cast<float4*>(gr + 20) = make_float4(a20, a21, a22, a23);
    gr[24] = a24;
  }
}

// ---------------- K2: per-batch recurrence (512 blocks x 1 wave) -----------
// Weights in NAMED/PINNED registers (AGPR parking is fine); c broadcast via
// wave-uniform float4 LDS reads (13 ds_read + 1 ds_write per iter = minimum
// DS traffic); named gq0..gq3 prefetch regs, unconditionally reloaded
// (direct def -> waitcnt lands 4 bodies later). lanes 0-49: c; 50-54: key;
// 55-59: q.
__global__ __launch_bounds__(64) void k2_rec(
    const float* __restrict__ g, const float* __restrict__ WK2T,
    const float* __restrict__ bias2, const float* __restrict__ first_context,
    float* __restrict__ ctxg, float* __restrict__ keyg,
    float* __restrict__ qg) {
  __shared__ __align__(16) float c_lds[64];
  const int b = blockIdx.x;
  const int lane = threadIdx.x;

#define WDECL(j)                            \
  float w##j = WK2T[(j) * 64 + lane];       \
  asm volatile("" : "+v"(w##j));
  R50(WDECL)
  const float wz = 0.f;
  const float bias = bias2[lane];

  const float c0v = (lane < HH) ? first_context[lane] : 0.f;
  c_lds[lane] = (lane < HH) ? c0v : 0.f;  // [50..63] stay 0 forever
  if (lane < HH) ctxg[((size_t)b * 257 + 0) * HH + lane] = c0v;

  const int gslot = lane + (lane >= 25 ? 3 : 0);  // k1b's stride-56 layout
  const float* __restrict__ gbp = g + (size_t)b * TT * GST + gslot;
  // unconditional preloads (lanes >= 50 read junk in-bounds; never consumed)
  float gq0 = gbp[0 * GST];
  float gq1 = gbp[1 * GST];
  float gq2 = gbp[2 * GST];
  float gq3 = gbp[3 * GST];

#define KQ(J, wa, wb, wc, wd)                                            \
  {                                                                      \
    const float4 cq = *reinterpret_cast<const float4*>(&c_lds[J]);       \
    acc0 = fmaf(wa, cq.x, acc0);                                         \
    acc1 = fmaf(wb, cq.y, acc1);                                         \
    acc2 = fmaf(wc, cq.z, acc2);                                         \
    acc3 = fmaf(wd, cq.w, acc3);                                         \
  }
#define DOT50R                                                           \
  float acc0 = 0.f, acc1 = 0.f, acc2 = 0.f, acc3 = 0.f;                  \
  KQ(0, w0, w1, w2, w3) KQ(4, w4, w5, w6, w7)                            \
  KQ(8, w8, w9, w10, w11) KQ(12, w12, w13, w14, w15)                     \
  KQ(16, w16, w17, w18, w19) KQ(20, w20, w21, w22, w23)                  \
  KQ(24, w24, w25, w26, w27) KQ(28, w28, w29, w30, w31)                  \
  KQ(32, w32, w33, w34, w35) KQ(36, w36, w37, w38, w39)                  \
  KQ(40, w40, w41, w42, w43) KQ(44, w44, w45, w46, w47)                  \
  KQ(48, w48, w49, wz, wz)                                               \
  const float acc = (acc0 + acc1) + (acc2 + acc3);

#define BODY(RR, GQ)                                                     \
  {                                                                      \
    const int t = tg4 + RR;                                              \
    DOT50R                                                               \
    if (lane >= HH && lane < HH + KK)                                    \
      keyg[((size_t)b * KK + (lane - HH)) * 257 + t] = acc + bias;       \
    if (lane >= HH + KK && lane < HH + 2 * KK && t >= 1)                 \
      qg[((size_t)b * KK + (lane - HH - KK)) * 256 + (t - 1)] =          \
          acc + bias;                                                    \
    const float cn = fmaxf(acc + GQ, 0.f);                               \
    GQ = gbp[(size_t)min(t + 4, TT - 1) * GST]; /* uncond, direct def */ \
    if (lane < HH) {                                                     \
      ctxg[((size_t)b * 257 + (t + 1)) * HH + lane] = cn;                \
      c_lds[lane] = cn;  /* in-wave DS order: visible next body */       \
    }                                                                    \
  }

#pragma unroll 1
  for (int tg4 = 0; tg4 < TT; tg4 += 4) {
    BODY(0, gq0) BODY(1, gq1) BODY(2, gq2) BODY(3, gq3)
  }

  {  // tail t = TT: key[TT] of c_TT, and q[TT-1]
    DOT50R
    if (lane >= HH && lane < HH + KK)
      keyg[((size_t)b * KK + (lane - HH)) * 257 + TT] = acc + bias;
    if (lane >= HH + KK && lane < HH + 2 * KK)
      qg[((size_t)b * KK + (lane - HH - KK)) * 256 + (TT - 1)] = acc + bias;
  }
}

// ---------------- K3: MFMA flash attention, LDS-staged (unchanged) --------
__global__ __launch_bounds__(256, 4) void k3_attn(
    const float* __restrict__ ctxg, const float* __restrict__ keyg,
    const float* __restrict__ qg, const float* __restrict__ W_act,
    const float* __restrict__ b_act, float* __restrict__ out) {
  __shared__ __align__(16) float ct[64 * 66];   // [s_local][h]
  __shared__ __align__(16) float k_l[8 * 68];   // [k][s_local], rows 5-7 = 0
  __shared__ __align__(16) float o_l[64 * 66];  // [t_local][h]
  __shared__ float su_l[64];

  const int tid = threadIdx.x;
  const int bid = blockIdx.x;
  const int chunk = 3 - (bid >> 9);  // heavy-first
  const int b = bid & 511;
  const int tbase = chunk * 64;
  const int nst = min(tbase + 66, 257);
  const int ntiles = (nst + 63) >> 6;
  const int wave = tid >> 6;
  const int lane = tid & 63;
  const int lrow = lane & 15;
  const int lgrp = lane >> 4;
  const int tw = tbase + wave * 16;

  if (tid < 3 * 68) k_l[5 * 68 + tid] = 0.f;

  half4 qf;
#pragma unroll
  for (int i = 0; i < 4; ++i) {
    const int k = 4 * lgrp + i;
    qf[i] = (_Float16)((k < KK) ? qg[((size_t)b * KK + k) * 256 + tw + lrow]
                                : 0.f);
  }

  const f32x4 zf = {0.f, 0.f, 0.f, 0.f};
  f32x4 acc0 = zf, acc1 = zf, acc2 = zf, acc3 = zf;
  float su = 0.f;

#pragma unroll 1
  for (int tile = 0; tile < ntiles; ++tile) {
    __syncthreads();
    {
      const int r = tid >> 2;
      const int c0 = (tid & 3) * 16;
      const int srow = tile * 64 + r;
      const float* src = ctxg + ((size_t)b * 257 + srow) * HH;
      const bool sv = (srow < nst);
#pragma unroll
      for (int u = 0; u < 8; ++u) {
        const int c = c0 + u * 2;
        float2 v = make_float2(0.f, 0.f);
        if (sv && c < HH) v = *reinterpret_cast<const float2*>(src + c);
        *reinterpret_cast<float2*>(&ct[r * 66 + c]) = v;
      }
    }
    {
      for (int i = tid; i < KK * 64; i += 256) {
        const int k = i >> 6, sl = i & 63;
        const int s = tile * 64 + sl;
        k_l[k * 68 + sl] =
            (s <= TT) ? keyg[((size_t)b * KK + k) * 257 + s] : 0.f;
      }
    }
    __syncthreads();

    if (tile * 64 <= tw + 16) {
#pragma unroll 1
      for (int su16 = 0; su16 < 4; ++su16) {
        const int sb = tile * 64 + su16 * 16;
        if (sb > tw + 16) break;

        half4 kf;
#pragma unroll
        for (int i = 0; i < 4; ++i)
          kf[i] = (_Float16)k_l[(4 * lgrp + i) * 68 + su16 * 16 + lrow];

        const f32x4 sc =
            __builtin_amdgcn_mfma_f32_16x16x16f16(kf, qf, zf, 0, 0, 0);

        half4 pa;
#pragma unroll
        for (int r = 0; r < 4; ++r) {
          const int s = sb + 4 * lgrp + r;
          const float p = (s <= tw + lrow + 1) ? __expf(sc[r]) : 0.f;
          su += p;
          pa[r] = (_Float16)p;
        }

        const int vbase = su16 * 16 + 4 * lgrp;
#define PVHT(HT, ACC)                                                     \
  {                                                                       \
    half4 vf;                                                             \
    vf[0] = (_Float16)ct[(vbase + 0) * 66 + lrow + 16 * HT];              \
    vf[1] = (_Float16)ct[(vbase + 1) * 66 + lrow + 16 * HT];              \
    vf[2] = (_Float16)ct[(vbase + 2) * 66 + lrow + 16 * HT];              \
    vf[3] = (_Float16)ct[(vbase + 3) * 66 + lrow + 16 * HT];              \
    ACC = __builtin_amdgcn_mfma_f32_16x16x16f16(pa, vf, ACC, 0, 0, 0);    \
  }
        PVHT(0, acc0) PVHT(1, acc1) PVHT(2, acc2) PVHT(3, acc3)
      }
    }
  }

  su += __shfl_xor(su, 16, 64);
  su += __shfl_xor(su, 32, 64);
  if (lane < 16) su_l[wave * 16 + lane] = su;

#pragma unroll
  for (int r = 0; r < 4; ++r) {
    const int trow = wave * 16 + 4 * lgrp + r;
    o_l[trow * 66 + lrow + 0] = acc0[r];
    o_l[trow * 66 + lrow + 16] = acc1[r];
    o_l[trow * 66 + lrow + 32] = acc2[r];
    o_l[trow * 66 + lrow + 48] = acc3[r];
  }
  __syncthreads();

  {
    const int tl = tid >> 2;
    const int a = tid & 3;
    const float inv = 1.f / su_l[tl];
    const float* orow = &o_l[tl * 66];
    const float* wrow = W_act + a * HH;
    float s0 = 0.f, s1 = 0.f;
#pragma unroll
    for (int h = 0; h < HH; h += 2) {
      s0 = fmaf(orow[h], wrow[h], s0);
      s1 = fmaf(orow[h + 1], wrow[h + 1], s1);
    }
    out[((size_t)(tbase + tl) * BB + b) * AA + a] =
        fmaf(s0 + s1, inv, b_act[a]);
  }
}

extern "C" void kernel_launch(void* const* d_in, const int* in_sizes, int n_in,
                              void* d_out, int out_size, void* d_ws,
                              size_t ws_size, hipStream_t stream) {
  const float* x = (const float*)d_in[0];
  const float* W_in = (const float*)d_in[1];
  const float* b_in = (const float*)d_in[2];
  const float* W_ctx = (const float*)d_in[3];
  const float* b_ctx = (const float*)d_in[4];
  const float* W_key = (const float*)d_in[5];
  const float* b_key = (const float*)d_in[6];
  const float* W_q = (const float*)d_in[7];
  const float* b_q = (const float*)d_in[8];
  const float* fc = (const float*)d_in[9];
  const float* W_act = (const float*)d_in[10];
  const float* b_act = (const float*)d_in[11];
  float* out = (float*)d_out;
  float* ws = (float*)d_ws;

  float* WT = ws;                                  // 128*52
  float* WHT = ws + 8192;                          // 50*52
  float* WK2T = ws + 12288;                        // 50*64
  float* bias2 = ws + 15616;                       // 64
  float* g = ws + 16384;                           // 131072*56 (+64 pad)
  float* hbufT = g + (size_t)NROW * GST + 64;      // 50*131072
  float* ctxg = hbufT;                             // alias: dead after k1b
  float* keyg = hbufT + (size_t)BB * 257 * HH;     // 512*5*257
  float* qg = keyg + (size_t)BB * KK * 257;        // 512*5*256
  // total ~61 MB

  hipLaunchKernelGGL(k0_prep, dim3(26), dim3(256), 0, stream, W_in, W_ctx,
                     W_key, W_q, b_key, b_q, WT, WHT, WK2T, bias2);
  hipLaunchKernelGGL(k1a, dim3(512), dim3(256), 0, stream, x, WT, b_in, hbufT);
  hipLaunchKernelGGL(k1b, dim3(512), dim3(256), 0, stream, hbufT, WHT, b_ctx,
                     g);
  hipLaunchKernelGGL(k2_rec, dim3(512), dim3(64), 0, stream, g, WK2T, bias2,
                     fc, ctxg, keyg, qg);
  hipLaunchKernelGGL(k3_attn, dim3(2048), dim3(256), 0, stream, ctxg, keyg, qg,
                     W_act, b_act, out);
}